// Round 5
// baseline (340.037 us; speedup 1.0000x reference)
//
#include <hip/hip_runtime.h>
#include <math.h>

#define DEV __device__ __forceinline__

constexpr int N_TRAIN = 131072;
constexpr int M_TEST  = 65536;
constexpr int T_TOT   = N_TRAIN + M_TEST;  // 196608
constexpr int TPB     = 128;               // 2 waves/block (even SIMD pairing)
constexpr int WPB     = 2;
constexpr int NB      = 1536;              // 1536*128 = 196608 -> 1 elem/thread
constexpr int NGRP_BAR = 16;               // barrier fan-in groups
constexpr int BLKS_PER_GRP = NB / NGRP_BAR; // 96
constexpr int PER_T   = 12;                // aggregates per thread in mid scans (1536/128)

// ---------------- 3x3 helpers (row-major float[9]) ----------------
DEV void mm(const float* X, const float* Y, float* Z) {
#pragma unroll
  for (int i = 0; i < 3; ++i)
#pragma unroll
    for (int j = 0; j < 3; ++j)
      Z[i*3+j] = X[i*3]*Y[j] + X[i*3+1]*Y[3+j] + X[i*3+2]*Y[6+j];
}
DEV void mmnt(const float* X, const float* Y, float* Z) { // X * Y^T
#pragma unroll
  for (int i = 0; i < 3; ++i)
#pragma unroll
    for (int j = 0; j < 3; ++j)
      Z[i*3+j] = X[i*3]*Y[j*3] + X[i*3+1]*Y[j*3+1] + X[i*3+2]*Y[j*3+2];
}
DEV void mtn(const float* X, const float* Y, float* Z) { // X^T * Y
#pragma unroll
  for (int i = 0; i < 3; ++i)
#pragma unroll
    for (int j = 0; j < 3; ++j)
      Z[i*3+j] = X[i]*Y[j] + X[3+i]*Y[3+j] + X[6+i]*Y[6+j];
}
DEV void mv(const float* X, const float* v, float* w) {
#pragma unroll
  for (int i = 0; i < 3; ++i) w[i] = X[i*3]*v[0] + X[i*3+1]*v[1] + X[i*3+2]*v[2];
}
DEV void mtv(const float* X, const float* v, float* w) {
#pragma unroll
  for (int i = 0; i < 3; ++i) w[i] = X[i]*v[0] + X[3+i]*v[1] + X[6+i]*v[2];
}
// fp32 inverse — used for Mx = I + C*J (det>=1, well-conditioned)
DEV void inv3f(const float* m, float* o) {
  float c00 = m[4]*m[8] - m[5]*m[7];
  float c10 = m[5]*m[6] - m[3]*m[8];
  float c20 = m[3]*m[7] - m[4]*m[6];
  float det = m[0]*c00 + m[1]*c10 + m[2]*c20;
  float id = 1.0f / det;
  o[0] = c00*id; o[1] = (m[2]*m[7]-m[1]*m[8])*id; o[2] = (m[1]*m[5]-m[2]*m[4])*id;
  o[3] = c10*id; o[4] = (m[0]*m[8]-m[2]*m[6])*id; o[5] = (m[2]*m[3]-m[0]*m[5])*id;
  o[6] = c20*id; o[7] = (m[1]*m[6]-m[0]*m[7])*id; o[8] = (m[0]*m[4]-m[1]*m[3])*id;
}
// double-cofactor inverse — used for Pp^-1 (cond ~1e6+, cancellation hedge)
DEV void inv3d(const float* mf_, float* o) {
  double m0=mf_[0], m1=mf_[1], m2=mf_[2], m3=mf_[3], m4=mf_[4],
         m5=mf_[5], m6=mf_[6], m7=mf_[7], m8=mf_[8];
  double c00 = m4*m8 - m5*m7;
  double c10 = m5*m6 - m3*m8;
  double c20 = m3*m7 - m4*m6;
  double det = m0*c00 + m1*c10 + m2*c20;
  double id = 1.0 / det;
  o[0] = (float)(c00*id); o[1] = (float)((m2*m7-m1*m8)*id); o[2] = (float)((m1*m5-m2*m4)*id);
  o[3] = (float)(c10*id); o[4] = (float)((m0*m8-m2*m6)*id); o[5] = (float)((m2*m3-m0*m5)*id);
  o[6] = (float)(c20*id); o[7] = (float)((m1*m6-m0*m7)*id); o[8] = (float)((m0*m4-m1*m3)*id);
}
DEV void symm(float* P) {
  float a = 0.5f*(P[1]+P[3]), b = 0.5f*(P[2]+P[6]), c = 0.5f*(P[5]+P[7]);
  P[1]=P[3]=a; P[2]=P[6]=b; P[5]=P[7]=c;
}
DEV void st_state(const float* m, const float* P, float* g) {
  g[0]=m[0]; g[1]=m[1]; g[2]=m[2];
  g[3]=P[0]; g[4]=P[1]; g[5]=P[2]; g[6]=P[4]; g[7]=P[5]; g[8]=P[8];
}
DEV void ld_state(const float* g, float* m, float* P) {
  m[0]=g[0]; m[1]=g[1]; m[2]=g[2];
  P[0]=g[3]; P[1]=g[4]; P[2]=g[5];
  P[3]=g[4]; P[4]=g[6]; P[5]=g[7];
  P[6]=g[5]; P[7]=g[7]; P[8]=g[8];
}

// ---------------- model ----------------
struct Model { float lam, v, kap, l4; };
DEV Model make_model(const float* varp, const float* ellp) {
  Model M; M.v = varp[0];
  float ell = ellp[0];
  M.lam = sqrtf(5.0f) / ell;
  M.kap = M.lam * M.lam / 3.0f;
  float l2 = M.lam * M.lam;
  M.l4 = l2 * l2;
  return M;
}
DEV void pinf(const Model& M, float* P) {
  float vk = M.v * M.kap;
  P[0]=M.v; P[1]=0;  P[2]=-vk;
  P[3]=0;   P[4]=vk; P[5]=0;
  P[6]=-vk; P[7]=0;  P[8]=M.v*M.l4;
}
DEV void make_AQ(const Model& M, float dt, float* A, float* Q) {
  float lam = M.lam, l2 = lam*lam, l3 = l2*lam, l4 = M.l4;
  float e = __expf(-lam * dt);
  float h = 0.5f * dt * dt;
  A[0] = e*(1.0f + dt*lam + h*l2);
  A[1] = e*(dt + 2.0f*h*lam);
  A[2] = e*h;
  A[3] = e*(-h*l3);
  A[4] = e*(1.0f + dt*lam - 2.0f*h*l2);
  A[5] = e*(dt - h*lam);
  A[6] = e*(-dt*l3 + h*l4);
  A[7] = e*(-3.0f*dt*l2 + 2.0f*h*l3);
  A[8] = e*(1.0f - 2.0f*dt*lam + h*l2);
  float vk = M.v * M.kap, vl4 = M.v * M.l4;
  float B[9];  // A * Pinf
#pragma unroll
  for (int i = 0; i < 3; ++i) {
    B[i*3+0] =  A[i*3+0]*M.v - A[i*3+2]*vk;
    B[i*3+1] =  A[i*3+1]*vk;
    B[i*3+2] = -A[i*3+0]*vk  + A[i*3+2]*vl4;
  }
  float Pi[9]; pinf(M, Pi);
#pragma unroll
  for (int i = 0; i < 3; ++i)
#pragma unroll
    for (int j = 0; j < 3; ++j)
      Q[i*3+j] = Pi[i*3+j] - (B[i*3]*A[j*3] + B[i*3+1]*A[j*3+1] + B[i*3+2]*A[j*3+2]);
}

// ---------------- filter scan element ----------------
struct FE { float A[9]; float b[3]; float C[9]; float h[3]; float J[9]; };

// packed-27 contiguous: [A0..8][b0..2][C00,C01,C02,C11,C12,C22][h0..2][J sym 6]
DEV void fe_store27(const FE& e, float* g) {
#pragma unroll
  for (int i=0;i<9;++i) g[i]=e.A[i];
  g[9]=e.b[0]; g[10]=e.b[1]; g[11]=e.b[2];
  g[12]=e.C[0]; g[13]=e.C[1]; g[14]=e.C[2]; g[15]=e.C[4]; g[16]=e.C[5]; g[17]=e.C[8];
  g[18]=e.h[0]; g[19]=e.h[1]; g[20]=e.h[2];
  g[21]=e.J[0]; g[22]=e.J[1]; g[23]=e.J[2]; g[24]=e.J[4]; g[25]=e.J[5]; g[26]=e.J[8];
}
DEV FE fe_load27(const float* g) {
  FE e;
#pragma unroll
  for (int i=0;i<9;++i) e.A[i]=g[i];
  e.b[0]=g[9]; e.b[1]=g[10]; e.b[2]=g[11];
  e.C[0]=g[12]; e.C[1]=g[13]; e.C[2]=g[14]; e.C[3]=g[13]; e.C[4]=g[15];
  e.C[5]=g[16]; e.C[6]=g[14]; e.C[7]=g[16]; e.C[8]=g[17];
  e.h[0]=g[18]; e.h[1]=g[19]; e.h[2]=g[20];
  e.J[0]=g[21]; e.J[1]=g[22]; e.J[2]=g[23]; e.J[3]=g[22]; e.J[4]=g[24];
  e.J[5]=g[25]; e.J[6]=g[23]; e.J[7]=g[25]; e.J[8]=g[26];
  return e;
}
DEV FE fe_shfl_up(const FE& e, int d) {
  FE o;
#pragma unroll
  for (int i=0;i<9;++i) o.A[i]=__shfl_up(e.A[i], d, 64);
#pragma unroll
  for (int i=0;i<3;++i) o.b[i]=__shfl_up(e.b[i], d, 64);
  float c0=__shfl_up(e.C[0],d,64), c1=__shfl_up(e.C[1],d,64), c2=__shfl_up(e.C[2],d,64),
        c4=__shfl_up(e.C[4],d,64), c5=__shfl_up(e.C[5],d,64), c8=__shfl_up(e.C[8],d,64);
  o.C[0]=c0; o.C[1]=c1; o.C[2]=c2; o.C[3]=c1; o.C[4]=c4; o.C[5]=c5;
  o.C[6]=c2; o.C[7]=c5; o.C[8]=c8;
#pragma unroll
  for (int i=0;i<3;++i) o.h[i]=__shfl_up(e.h[i], d, 64);
  float j0=__shfl_up(e.J[0],d,64), j1=__shfl_up(e.J[1],d,64), j2=__shfl_up(e.J[2],d,64),
        j4=__shfl_up(e.J[4],d,64), j5=__shfl_up(e.J[5],d,64), j8=__shfl_up(e.J[8],d,64);
  o.J[0]=j0; o.J[1]=j1; o.J[2]=j2; o.J[3]=j1; o.J[4]=j4; o.J[5]=j5;
  o.J[6]=j2; o.J[7]=j5; o.J[8]=j8;
  return o;
}
DEV FE build_felem(const Model& M, float dt, float obsf, float rf, float Rf_, bool first) {
  FE E;
  float r = rf, R = Rf_;
  float g = (obsf > 0.5f) ? 1.0f : 0.0f;
  if (first) {
#pragma unroll
    for (int i=0;i<9;++i){ E.A[i]=0.0f; E.J[i]=0.0f; }
    E.h[0]=E.h[1]=E.h[2]=0.0f;
    float Pi[9]; pinf(M, Pi);
    float S = Pi[0] + R;
    float f = g / S;
    float K0=Pi[0]*f, K1=Pi[3]*f, K2=Pi[6]*f;
    E.b[0]=K0*r; E.b[1]=K1*r; E.b[2]=K2*r;
    E.C[0]=Pi[0]-S*K0*K0; E.C[1]=Pi[1]-S*K0*K1; E.C[2]=Pi[2]-S*K0*K2;
    E.C[3]=Pi[3]-S*K1*K0; E.C[4]=Pi[4]-S*K1*K1; E.C[5]=Pi[5]-S*K1*K2;
    E.C[6]=Pi[6]-S*K2*K0; E.C[7]=Pi[7]-S*K2*K1; E.C[8]=Pi[8]-S*K2*K2;
    return E;
  }
  float Am[9], Q[9]; make_AQ(M, dt, Am, Q);
  float S = Q[0] + R, iS = g / S;   // gated: obs=0 -> K=0, A=Am, C=Q, h=0, J=0
  float K0=Q[0]*iS, K1=Q[3]*iS, K2=Q[6]*iS;
#pragma unroll
  for (int j = 0; j < 3; ++j) {
    E.A[j]   = Am[j]   - K0*Am[j];
    E.A[3+j] = Am[3+j] - K1*Am[j];
    E.A[6+j] = Am[6+j] - K2*Am[j];
    E.C[j]   = Q[j]    - K0*Q[j];
    E.C[3+j] = Q[3+j]  - K1*Q[j];
    E.C[6+j] = Q[6+j]  - K2*Q[j];
  }
  E.b[0]=K0*r; E.b[1]=K1*r; E.b[2]=K2*r;
  float riS = r*iS;
  E.h[0]=Am[0]*riS; E.h[1]=Am[1]*riS; E.h[2]=Am[2]*riS;
#pragma unroll
  for (int i = 0; i < 3; ++i)
#pragma unroll
    for (int j = 0; j < 3; ++j)
      E.J[i*3+j] = Am[i]*Am[j]*iS;
  return E;
}
// compose: x earlier, y later
DEV FE fcompose(const FE& x, const FE& y) {
  const float *A1=x.A,*b1=x.b,*C1=x.C,*h1=x.h,*J1=x.J;
  const float *A2=y.A,*b2=y.b,*C2=y.C,*h2=y.h,*J2=y.J;
  FE o;
  float Mx[9]; mm(C1,J2,Mx); Mx[0]+=1.0f; Mx[4]+=1.0f; Mx[8]+=1.0f;
  float Mi[9]; inv3f(Mx,Mi);
  float T1[9]; mm(A2,Mi,T1);
  mm(T1,A1,o.A);
  float u[3]; mv(C1,h2,u); u[0]+=b1[0]; u[1]+=b1[1]; u[2]+=b1[2];
  mv(T1,u,o.b); o.b[0]+=b2[0]; o.b[1]+=b2[1]; o.b[2]+=b2[2];
  float t2[9]; mm(T1,C1,t2);
  mmnt(t2,A2,o.C);
#pragma unroll
  for (int i=0;i<9;++i) o.C[i]+=C2[i];
  float tmp[9]; mm(Mi,A1,tmp);
  float w[3]; mv(J2,b1,w);
  w[0]=h2[0]-w[0]; w[1]=h2[1]-w[1]; w[2]=h2[2]-w[2];
  mtv(tmp,w,o.h); o.h[0]+=h1[0]; o.h[1]+=h1[1]; o.h[2]+=h1[2];
  float V[9]; mm(J2,A1,V);
  mtn(tmp,V,o.J);
#pragma unroll
  for (int i=0;i<9;++i) o.J[i]+=J1[i];
  symm(o.C); symm(o.J);
  return o;
}
// apply element y (later) to a state (m,P)
DEV void fapply(const FE& y, float* m, float* P) {
  float Mx[9]; mm(P, y.J, Mx); Mx[0]+=1.0f; Mx[4]+=1.0f; Mx[8]+=1.0f;
  float Mi[9]; inv3f(Mx, Mi);
  float T1[9]; mm(y.A, Mi, T1);
  float u[3]; mv(P, y.h, u); u[0]+=m[0]; u[1]+=m[1]; u[2]+=m[2];
  float mn[3]; mv(T1, u, mn);
  m[0]=mn[0]+y.b[0]; m[1]=mn[1]+y.b[1]; m[2]=mn[2]+y.b[2];
  float t2[9]; mm(T1, P, t2);
  float Pn[9]; mmnt(t2, y.A, Pn);
#pragma unroll
  for (int i=0;i<9;++i) P[i]=Pn[i]+y.C[i];
  symm(P);
}
// plain Kalman step (replay)
DEV void fstep(const Model& M, float dt, float obsf, float rf, float Rf_,
               float* m, float* P) {
  float A[9], Q[9]; make_AQ(M, dt, A, Q);
  float mp[3]; mv(A, m, mp);
  float W[9]; mmnt(P, A, W);      // P A^T
  float Pp[9]; mm(A, W, Pp);
#pragma unroll
  for (int i=0;i<9;++i) Pp[i]+=Q[i];
  float S = Pp[0] + Rf_;
  float f = (obsf > 0.5f) ? (1.0f/S) : 0.0f;
  float K0=Pp[0]*f, K1=Pp[3]*f, K2=Pp[6]*f;
  float v = rf - mp[0];
  m[0]=mp[0]+K0*v; m[1]=mp[1]+K1*v; m[2]=mp[2]+K2*v;
  P[0]=Pp[0]-S*K0*K0; P[1]=Pp[1]-S*K0*K1; P[2]=Pp[2]-S*K0*K2;
  P[3]=Pp[3]-S*K1*K0; P[4]=Pp[4]-S*K1*K1; P[5]=Pp[5]-S*K1*K2;
  P[6]=Pp[6]-S*K2*K0; P[7]=Pp[7]-S*K2*K1; P[8]=Pp[8]-S*K2*K2;
  symm(P);
}

// ---------------- smoother affine map ----------------
struct SE { float G[9]; float c[3]; float U[9]; };

DEV SE se_identity() {
  SE s;
#pragma unroll
  for (int i=0;i<9;++i){ s.G[i]=0.0f; s.U[i]=0.0f; }
  s.G[0]=s.G[4]=s.G[8]=1.0f;
  s.c[0]=s.c[1]=s.c[2]=0.0f;
  return s;
}
DEV void se_store(const SE& s, float* g) {   // contiguous packed-18
#pragma unroll
  for (int i=0;i<9;++i) g[i]=s.G[i];
  g[9]=s.c[0]; g[10]=s.c[1]; g[11]=s.c[2];
  g[12]=s.U[0]; g[13]=s.U[1]; g[14]=s.U[2]; g[15]=s.U[4]; g[16]=s.U[5]; g[17]=s.U[8];
}
DEV SE se_load(const float* g) {
  SE s;
#pragma unroll
  for (int i=0;i<9;++i) s.G[i]=g[i];
  s.c[0]=g[9]; s.c[1]=g[10]; s.c[2]=g[11];
  s.U[0]=g[12]; s.U[1]=g[13]; s.U[2]=g[14];
  s.U[3]=g[13]; s.U[4]=g[15]; s.U[5]=g[16];
  s.U[6]=g[14]; s.U[7]=g[16]; s.U[8]=g[17];
  return s;
}
DEV SE se_shfl_down(const SE& s, int d) {
  SE o;
#pragma unroll
  for (int i=0;i<9;++i) o.G[i]=__shfl_down(s.G[i], d, 64);
#pragma unroll
  for (int i=0;i<3;++i) o.c[i]=__shfl_down(s.c[i], d, 64);
  float u0=__shfl_down(s.U[0],d,64), u1=__shfl_down(s.U[1],d,64), u2=__shfl_down(s.U[2],d,64),
        u4=__shfl_down(s.U[4],d,64), u5=__shfl_down(s.U[5],d,64), u8=__shfl_down(s.U[8],d,64);
  o.U[0]=u0; o.U[1]=u1; o.U[2]=u2; o.U[3]=u1; o.U[4]=u4; o.U[5]=u5;
  o.U[6]=u2; o.U[7]=u5; o.U[8]=u8;
  return o;
}
// x earlier in time (applied LAST, since smoother runs backward)
DEV SE scompose(const SE& x, const SE& y) {
  SE o;
  mm(x.G, y.G, o.G);
  float t[3]; mv(x.G, y.c, t);
  o.c[0]=t[0]+x.c[0]; o.c[1]=t[1]+x.c[1]; o.c[2]=t[2]+x.c[2];
  float T[9]; mm(x.G, y.U, T);
  mmnt(T, x.G, o.U);
#pragma unroll
  for (int i=0;i<9;++i) o.U[i]+=x.U[i];
  symm(o.U);
  return o;
}
DEV void sapply(const SE& s, float* m, float* P) {
  float t[3]; mv(s.G, m, t);
  float T[9]; mm(s.G, P, T);
  float Pn[9]; mmnt(T, s.G, Pn);
  m[0]=t[0]+s.c[0]; m[1]=t[1]+s.c[1]; m[2]=t[2]+s.c[2];
#pragma unroll
  for (int i=0;i<9;++i) P[i]=Pn[i]+s.U[i];
  symm(P);
}
DEV SE selem_from_state(const Model& M, const float* m, const float* P, float dtn) {
  SE s;
  float A[9], Q[9]; make_AQ(M, dtn, A, Q);
  float W[9]; mmnt(P, A, W);      // P A^T
  float Pp[9]; mm(A, W, Pp);
#pragma unroll
  for (int j=0;j<9;++j) Pp[j]+=Q[j];
  float Pi_[9]; inv3d(Pp, Pi_);    // ill-conditioned -> double cofactors
  mm(W, Pi_, s.G);                 // G = P A^T Pp^-1
  float mp[3]; mv(A, m, mp);
  float gm[3]; mv(s.G, mp, gm);
  s.c[0]=m[0]-gm[0]; s.c[1]=m[1]-gm[1]; s.c[2]=m[2]-gm[2];
  float GW[9]; mmnt(s.G, W, GW);   // G Pp G^T
#pragma unroll
  for (int j=0;j<9;++j) s.U[j]=P[j]-GW[j];
  symm(s.U);
  return s;
}

// ---------------- device-wide barrier (two-level, agent scope) ----------------
// Spin is RELAXED (no per-poll cache invalidate); one acquire fence on exit.
DEV void grid_sync(int* bar, int grp) {
  __syncthreads();
  if (threadIdx.x == 0) {
    int* gen = bar + 257;
    int g = __hip_atomic_load(gen, __ATOMIC_RELAXED, __HIP_MEMORY_SCOPE_AGENT);
    asm volatile("s_waitcnt vmcnt(0)" ::: "memory");   // g in hand before arrival
    int* gc = bar + grp*16;
    if (__hip_atomic_fetch_add(gc, 1, __ATOMIC_RELEASE, __HIP_MEMORY_SCOPE_AGENT)
        == BLKS_PER_GRP-1) {
      __hip_atomic_store(gc, 0, __ATOMIC_RELAXED, __HIP_MEMORY_SCOPE_AGENT);
      int* cnt = bar + 256;
      if (__hip_atomic_fetch_add(cnt, 1, __ATOMIC_RELEASE, __HIP_MEMORY_SCOPE_AGENT)
          == NGRP_BAR-1) {
        __hip_atomic_store(cnt, 0, __ATOMIC_RELAXED, __HIP_MEMORY_SCOPE_AGENT);
        __hip_atomic_store(gen, g+1, __ATOMIC_RELEASE, __HIP_MEMORY_SCOPE_AGENT);
      }
    }
    while (__hip_atomic_load(gen, __ATOMIC_RELAXED, __HIP_MEMORY_SCOPE_AGENT) == g) {
      __builtin_amdgcn_s_sleep(1);
    }
    __builtin_amdgcn_fence(__ATOMIC_ACQUIRE, "agent");
  }
  __syncthreads();
}

// ================= kernels =================
__global__ void k_init(int* bar) {
  int i = threadIdx.x;
  if (i < 258) bar[i] = 0;
}

// Persistent kernel, 3 grid barriers, 1 elem/thread, 1536 blocks x 2 waves.
// __launch_bounds__(128,4): VGPR<=128 -> 8 blocks/CU capacity = 2048 >= 1536
// (33% slack — round 4 deadlocked at exact capacity with uneven 6-wave blocks).
// Steady state ~6 blocks/CU = 12 waves/CU (2x round 3's TLP; it was latency-bound).
// Mid-scans: 1536 aggregates distributed 12/thread over 128 threads; per-thread
// prefix states parked in LDS; extraction is a <=11-step block-uniform walk.
__global__ __launch_bounds__(TPB, 4) void k_fused(
    const float* __restrict__ times, const float* __restrict__ tstar,
    const float* __restrict__ n1, const float* __restrict__ n2,
    const float* __restrict__ varp, const float* __restrict__ ellp,
    const float* __restrict__ mcp,
    float4* __restrict__ pk, int* __restrict__ oix,
    float* __restrict__ blkAgg, float* __restrict__ blkAggS,
    float* __restrict__ xT, int* __restrict__ bar, float* __restrict__ out) {
  __shared__ float ldsA[WPB][27];     // wave totals (FE 27 / SE 18)
  __shared__ float ldsB[TPB][18];     // per-thread prefix states (9) / suffix SEs (18)
  const int tid = threadIdx.x, b = blockIdx.x;
  const int l = tid & 63, w = tid >> 6;
  const int grp = b & (NGRP_BAR-1);
  Model M = make_model(varp, ellp);
  const float mc = mcp[0];

  // ---- phase 0: merge (1 item per thread) ----
  {
    int g = b*TPB + tid;
    if (g < N_TRAIN) {
      int i = g; float t = times[i];
      int lo = 0, hi = M_TEST;                 // count tstar strictly < t
      while (lo < hi) { int mid=(lo+hi)>>1; if (tstar[mid] < t) lo=mid+1; else hi=mid; }
      int p = i + lo;
      float s2 = n2[i];
      pk[p] = make_float4(t, n1[i]/s2 - mc, 1.0f/s2, 1.0f);
      oix[p] = -1;
    } else {
      int j = g - N_TRAIN; float t = tstar[j];
      int lo = 0, hi = N_TRAIN;                // count times <= t (stable: train first)
      while (lo < hi) { int mid=(lo+hi)>>1; if (times[mid] <= t) lo=mid+1; else hi=mid; }
      int p = j + lo;
      pk[p] = make_float4(t, 0.f, 1.f, 0.f);
      oix[p] = j;
    }
  }
  grid_sync(bar, grp);                          // A: wrote pk/oix; all read pk

  // ---- phase 1: forward scan (1 elem/thread); exclusive-in-block FE in regs ----
  const int i0 = b*TPB + tid;
  float4 q0 = pk[i0];
  float tm1 = (i0 > 0) ? pk[i0-1].x : 0.0f;
  float tn  = (i0 < T_TOT-1) ? pk[i0+1].x : 0.0f;   // preload for P3
  const float dt0 = (i0 == 0) ? 0.0f : (q0.x - tm1);
  FE ex; bool has;
  {
    FE run = build_felem(M, dt0, q0.w, q0.y, q0.z, i0 == 0);
    for (int d = 1; d < 64; d <<= 1) {
      FE oth = fe_shfl_up(run, d);
      FE c = fcompose(oth, run);
      if (l >= d) run = c;
    }
    if (l == 63) fe_store27(run, ldsA[w]);
    FE exw = fe_shfl_up(run, 1);
    __syncthreads();
    has = false;
    if (l > 0) { ex = exw; has = true; }
    for (int k = w-1; k >= 0; --k) {            // wave-uniform
      FE wk = fe_load27(ldsA[k]);
      ex = has ? fcompose(wk, ex) : wk;
      has = true;
    }
    if (tid == TPB-1) {                         // block aggregate
      FE agg = fcompose(fe_load27(ldsA[0]), run);
      fe_store27(agg, blkAgg + b*27);
    }
  }
  grid_sync(bar, grp);                          // B: wrote blkAgg; all read it

  // ---- phase 2: distributed mid-scan over 1536 FE aggregates -> entry state ----
  float mE[3], PE[9];
  {
    FE acc = fe_load27(blkAgg + (tid*PER_T)*27);
    for (int i = 1; i < PER_T; ++i)
      acc = fcompose(acc, fe_load27(blkAgg + (tid*PER_T+i)*27));
    FE run = acc;
    for (int d = 1; d < 64; d <<= 1) {
      FE oth = fe_shfl_up(run, d);
      FE c = fcompose(oth, run);
      if (l >= d) run = c;
    }
    __syncthreads();                            // ldsA[ ] free (phase-1 reads done)
    if (w == 0 && l == 63) fe_store27(run, ldsA[0]);
    __syncthreads();
    if (w == 1) run = fcompose(fe_load27(ldsA[0]), run);
    // run covers aggs [0, 12*tid+11]; includes agg 0 -> (b,C) is a state
    ldsB[tid][0]=run.b[0]; ldsB[tid][1]=run.b[1]; ldsB[tid][2]=run.b[2];
    ldsB[tid][3]=run.C[0]; ldsB[tid][4]=run.C[1]; ldsB[tid][5]=run.C[2];
    ldsB[tid][6]=run.C[4]; ldsB[tid][7]=run.C[5]; ldsB[tid][8]=run.C[8];
    __syncthreads();
    // extraction (redundant per thread; block-uniform): prefix over [0, b-1]
    int full = b / PER_T;                       // threads [0, full) fully inside prefix
    if (b == 0) {
      mE[0]=mE[1]=mE[2]=0.0f; pinf(M, PE);
    } else {
      if (full == 0) { mE[0]=mE[1]=mE[2]=0.0f; pinf(M, PE); }
      else ld_state(&ldsB[full-1][0], mE, PE);
      for (int i = full*PER_T; i < b; ++i) {    // <=11 block-uniform applies
        FE y = fe_load27(blkAgg + i*27);
        fapply(y, mE, PE);
      }
    }
  }

  // ---- phase 3: replay + smoother element + backward in-block SE scan ----
  float r0[5];
  {
    float m[3] = { mE[0], mE[1], mE[2] };
    float P[9];
#pragma unroll
    for (int i=0;i<9;++i) P[i]=PE[i];
    if (has) fapply(ex, m, P);
    fstep(M, dt0, q0.w, q0.y, q0.z, m, P);
    SE s;
    if (i0 == T_TOT-1) {
      s = se_identity();
      st_state(m, P, xT);
    } else {
      s = selem_from_state(M, m, P, tn - q0.x);
    }
    SE run = s;
    for (int d = 1; d < 64; d <<= 1) {
      SE oth = se_shfl_down(run, d);
      SE c = scompose(run, oth);
      if (l + d < 64) run = c;
    }
    SE sx = se_shfl_down(run, 1);
    __syncthreads();                            // ldsB reads of phase 2 done
    if (l == 0) se_store(run, ldsA[w]);
    __syncthreads();
    SE S; bool hs = false;
    if (l < 63) { S = sx; hs = true; }
    for (int k = w+1; k < WPB; ++k) {           // wave-uniform
      SE wk = se_load(ldsA[k]);
      S = hs ? scompose(S, wk) : wk;
      hs = true;
    }
    SE Mf = hs ? scompose(s, S) : s;
    r0[0]=Mf.G[0]; r0[1]=Mf.G[1]; r0[2]=Mf.G[2]; r0[3]=Mf.c[0]; r0[4]=Mf.U[0];
    if (tid == 0) se_store(Mf, blkAggS + b*18); // tid 0's Mf spans whole block
  }
  grid_sync(bar, grp);                          // D: wrote blkAggS/xT; all read

  // ---- phase 4: distributed mid-scan over 1536 SE aggregates -> exit state ----
  float mX[3], PX[9];
  {
    SE acc = se_load(blkAggS + (tid*PER_T)*18);
    for (int i = 1; i < PER_T; ++i)
      acc = scompose(acc, se_load(blkAggS + (tid*PER_T+i)*18));
    SE run = acc;
    for (int d = 1; d < 64; d <<= 1) {
      SE oth = se_shfl_down(run, d);
      SE c = scompose(run, oth);
      if (l + d < 64) run = c;
    }
    if (w == 1 && l == 0) se_store(run, ldsA[0]);   // wave-1 total (aggs [768,1535])
    __syncthreads();
    if (w == 0) run = scompose(run, se_load(ldsA[0]));
    // run = suffix over aggs [12*tid, 1535]
    se_store(run, ldsB[tid]);
    __syncthreads();
    mX[0]=xT[0]; mX[1]=xT[1]; mX[2]=xT[2];
    PX[0]=xT[3]; PX[1]=xT[4]; PX[2]=xT[5];
    PX[3]=xT[4]; PX[4]=xT[6]; PX[5]=xT[7];
    PX[6]=xT[5]; PX[7]=xT[7]; PX[8]=xT[8];
    if (b < NB-1) {
      int e = b + 1;                            // suffix needed: aggs [e, NB-1]
      int ct = (e + PER_T - 1) / PER_T;         // first thread fully inside suffix
      if (ct < TPB) { SE sb = se_load(ldsB[ct]); sapply(sb, mX, PX); }
      for (int i = ct*PER_T - 1; i >= e; --i) { // <=11 block-uniform applies
        SE y = se_load(blkAggS + i*18);
        sapply(y, mX, PX);
      }
    }
    // mX/PX = smoothed state at first elem of block b+1 (b=NB-1: xT state)
  }

  // ---- phase 5: output ----
  {
    int jo = oix[i0];
    if (jo >= 0) {
      float mm0 = r0[0]*mX[0] + r0[1]*mX[1] + r0[2]*mX[2] + r0[3];
      float a0 = r0[0]*PX[0] + r0[1]*PX[3] + r0[2]*PX[6];
      float a1 = r0[0]*PX[1] + r0[1]*PX[4] + r0[2]*PX[7];
      float a2 = r0[0]*PX[2] + r0[1]*PX[5] + r0[2]*PX[8];
      float v00 = a0*r0[0] + a1*r0[1] + a2*r0[2] + r0[4];
      out[jo] = mm0 + mc; out[M_TEST + jo] = fmaxf(v00, 0.0f);
    }
  }
}

extern "C" void kernel_launch(void* const* d_in, const int* in_sizes, int n_in,
                              void* d_out, int out_size, void* d_ws, size_t ws_size,
                              hipStream_t stream) {
  const float* times = (const float*)d_in[0];
  const float* tstar = (const float*)d_in[1];
  const float* n1    = (const float*)d_in[2];
  const float* n2    = (const float*)d_in[3];
  const float* varp  = (const float*)d_in[4];
  const float* ellp  = (const float*)d_in[5];
  const float* mcp   = (const float*)d_in[6];
  float* out = (float*)d_out;

  size_t off = 0;
  auto take = [&](size_t bytes) {
    char* p = (char*)d_ws + off;
    off += (bytes + 255) & ~(size_t)255;
    return (void*)p;
  };
  float4* pk      = (float4*)take(sizeof(float4) * T_TOT);
  int*    oix     = (int*)   take(sizeof(int)    * T_TOT);
  float*  blkAgg  = (float*) take(sizeof(float)  * 27 * NB);
  float*  blkAggS = (float*) take(sizeof(float)  * 18 * NB);
  float*  xT      = (float*) take(sizeof(float)  * 16);
  int*    bar     = (int*)   take(sizeof(int)    * 512);
  (void)ws_size; (void)in_sizes; (void)n_in; (void)out_size;

  k_init<<<1, 512, 0, stream>>>(bar);
  k_fused<<<NB, TPB, 0, stream>>>(times, tstar, n1, n2, varp, ellp, mcp,
                                  pk, oix, blkAgg, blkAggS, xT, bar, out);
}

// Round 6
// 189.907 us; speedup vs baseline: 1.7905x; 1.7905x over previous
//
#include <hip/hip_runtime.h>
#include <math.h>

#define DEV __device__ __forceinline__

constexpr int N_TRAIN = 131072;
constexpr int M_TEST  = 65536;
constexpr int T_TOT   = N_TRAIN + M_TEST;  // 196608
constexpr int TPB     = 128;               // 2 waves/block (even SIMD pairing)
constexpr int WPB     = 2;
constexpr int NB      = 768;               // 3 blocks/CU, proven co-resident w/ slack
constexpr int EPW     = 128;               // elements per wave (2 per lane)
constexpr int EPB     = 256;               // elements per block (2 per thread)
constexpr int NGRP_BAR = 16;               // barrier fan-in groups
constexpr int BLKS_PER_GRP = NB / NGRP_BAR; // 48
constexpr int PER_T   = 6;                 // aggregates per thread in mid scans (768/128)

// ---------------- 3x3 helpers (row-major float[9]) ----------------
DEV void mm(const float* X, const float* Y, float* Z) {
#pragma unroll
  for (int i = 0; i < 3; ++i)
#pragma unroll
    for (int j = 0; j < 3; ++j)
      Z[i*3+j] = X[i*3]*Y[j] + X[i*3+1]*Y[3+j] + X[i*3+2]*Y[6+j];
}
DEV void mmnt(const float* X, const float* Y, float* Z) { // X * Y^T
#pragma unroll
  for (int i = 0; i < 3; ++i)
#pragma unroll
    for (int j = 0; j < 3; ++j)
      Z[i*3+j] = X[i*3]*Y[j*3] + X[i*3+1]*Y[j*3+1] + X[i*3+2]*Y[j*3+2];
}
DEV void mtn(const float* X, const float* Y, float* Z) { // X^T * Y
#pragma unroll
  for (int i = 0; i < 3; ++i)
#pragma unroll
    for (int j = 0; j < 3; ++j)
      Z[i*3+j] = X[i]*Y[j] + X[3+i]*Y[3+j] + X[6+i]*Y[6+j];
}
DEV void mv(const float* X, const float* v, float* w) {
#pragma unroll
  for (int i = 0; i < 3; ++i) w[i] = X[i*3]*v[0] + X[i*3+1]*v[1] + X[i*3+2]*v[2];
}
DEV void mtv(const float* X, const float* v, float* w) {
#pragma unroll
  for (int i = 0; i < 3; ++i) w[i] = X[i]*v[0] + X[3+i]*v[1] + X[6+i]*v[2];
}
// fp32 inverse — used for Mx = I + C*J (det>=1, well-conditioned)
DEV void inv3f(const float* m, float* o) {
  float c00 = m[4]*m[8] - m[5]*m[7];
  float c10 = m[5]*m[6] - m[3]*m[8];
  float c20 = m[3]*m[7] - m[4]*m[6];
  float det = m[0]*c00 + m[1]*c10 + m[2]*c20;
  float id = 1.0f / det;
  o[0] = c00*id; o[1] = (m[2]*m[7]-m[1]*m[8])*id; o[2] = (m[1]*m[5]-m[2]*m[4])*id;
  o[3] = c10*id; o[4] = (m[0]*m[8]-m[2]*m[6])*id; o[5] = (m[2]*m[3]-m[0]*m[5])*id;
  o[6] = c20*id; o[7] = (m[1]*m[6]-m[0]*m[7])*id; o[8] = (m[0]*m[4]-m[1]*m[3])*id;
}
// double-cofactor inverse — used for Pp^-1 (cond ~1e6+, cancellation hedge)
DEV void inv3d(const float* mf_, float* o) {
  double m0=mf_[0], m1=mf_[1], m2=mf_[2], m3=mf_[3], m4=mf_[4],
         m5=mf_[5], m6=mf_[6], m7=mf_[7], m8=mf_[8];
  double c00 = m4*m8 - m5*m7;
  double c10 = m5*m6 - m3*m8;
  double c20 = m3*m7 - m4*m6;
  double det = m0*c00 + m1*c10 + m2*c20;
  double id = 1.0 / det;
  o[0] = (float)(c00*id); o[1] = (float)((m2*m7-m1*m8)*id); o[2] = (float)((m1*m5-m2*m4)*id);
  o[3] = (float)(c10*id); o[4] = (float)((m0*m8-m2*m6)*id); o[5] = (float)((m2*m3-m0*m5)*id);
  o[6] = (float)(c20*id); o[7] = (float)((m1*m6-m0*m7)*id); o[8] = (float)((m0*m4-m1*m3)*id);
}
DEV void symm(float* P) {
  float a = 0.5f*(P[1]+P[3]), b = 0.5f*(P[2]+P[6]), c = 0.5f*(P[5]+P[7]);
  P[1]=P[3]=a; P[2]=P[6]=b; P[5]=P[7]=c;
}
DEV void st_state(const float* m, const float* P, float* g) {
  g[0]=m[0]; g[1]=m[1]; g[2]=m[2];
  g[3]=P[0]; g[4]=P[1]; g[5]=P[2]; g[6]=P[4]; g[7]=P[5]; g[8]=P[8];
}
DEV void ld_state(const float* g, float* m, float* P) {
  m[0]=g[0]; m[1]=g[1]; m[2]=g[2];
  P[0]=g[3]; P[1]=g[4]; P[2]=g[5];
  P[3]=g[4]; P[4]=g[6]; P[5]=g[7];
  P[6]=g[5]; P[7]=g[7]; P[8]=g[8];
}

// ---------------- model ----------------
struct Model { float lam, v, kap, l4; };
DEV Model make_model(const float* varp, const float* ellp) {
  Model M; M.v = varp[0];
  float ell = ellp[0];
  M.lam = sqrtf(5.0f) / ell;
  M.kap = M.lam * M.lam / 3.0f;
  float l2 = M.lam * M.lam;
  M.l4 = l2 * l2;
  return M;
}
DEV void pinf(const Model& M, float* P) {
  float vk = M.v * M.kap;
  P[0]=M.v; P[1]=0;  P[2]=-vk;
  P[3]=0;   P[4]=vk; P[5]=0;
  P[6]=-vk; P[7]=0;  P[8]=M.v*M.l4;
}
DEV void make_AQ(const Model& M, float dt, float* A, float* Q) {
  float lam = M.lam, l2 = lam*lam, l3 = l2*lam, l4 = M.l4;
  float e = __expf(-lam * dt);
  float h = 0.5f * dt * dt;
  A[0] = e*(1.0f + dt*lam + h*l2);
  A[1] = e*(dt + 2.0f*h*lam);
  A[2] = e*h;
  A[3] = e*(-h*l3);
  A[4] = e*(1.0f + dt*lam - 2.0f*h*l2);
  A[5] = e*(dt - h*lam);
  A[6] = e*(-dt*l3 + h*l4);
  A[7] = e*(-3.0f*dt*l2 + 2.0f*h*l3);
  A[8] = e*(1.0f - 2.0f*dt*lam + h*l2);
  float vk = M.v * M.kap, vl4 = M.v * M.l4;
  float B[9];  // A * Pinf
#pragma unroll
  for (int i = 0; i < 3; ++i) {
    B[i*3+0] =  A[i*3+0]*M.v - A[i*3+2]*vk;
    B[i*3+1] =  A[i*3+1]*vk;
    B[i*3+2] = -A[i*3+0]*vk  + A[i*3+2]*vl4;
  }
  float Pi[9]; pinf(M, Pi);
#pragma unroll
  for (int i = 0; i < 3; ++i)
#pragma unroll
    for (int j = 0; j < 3; ++j)
      Q[i*3+j] = Pi[i*3+j] - (B[i*3]*A[j*3] + B[i*3+1]*A[j*3+1] + B[i*3+2]*A[j*3+2]);
}

// ---------------- filter scan element ----------------
struct FE { float A[9]; float b[3]; float C[9]; float h[3]; float J[9]; };

// packed-27 contiguous: [A0..8][b0..2][C00,C01,C02,C11,C12,C22][h0..2][J sym 6]
DEV void fe_store27(const FE& e, float* g) {
#pragma unroll
  for (int i=0;i<9;++i) g[i]=e.A[i];
  g[9]=e.b[0]; g[10]=e.b[1]; g[11]=e.b[2];
  g[12]=e.C[0]; g[13]=e.C[1]; g[14]=e.C[2]; g[15]=e.C[4]; g[16]=e.C[5]; g[17]=e.C[8];
  g[18]=e.h[0]; g[19]=e.h[1]; g[20]=e.h[2];
  g[21]=e.J[0]; g[22]=e.J[1]; g[23]=e.J[2]; g[24]=e.J[4]; g[25]=e.J[5]; g[26]=e.J[8];
}
DEV FE fe_load27(const float* g) {
  FE e;
#pragma unroll
  for (int i=0;i<9;++i) e.A[i]=g[i];
  e.b[0]=g[9]; e.b[1]=g[10]; e.b[2]=g[11];
  e.C[0]=g[12]; e.C[1]=g[13]; e.C[2]=g[14]; e.C[3]=g[13]; e.C[4]=g[15];
  e.C[5]=g[16]; e.C[6]=g[14]; e.C[7]=g[16]; e.C[8]=g[17];
  e.h[0]=g[18]; e.h[1]=g[19]; e.h[2]=g[20];
  e.J[0]=g[21]; e.J[1]=g[22]; e.J[2]=g[23]; e.J[3]=g[22]; e.J[4]=g[24];
  e.J[5]=g[25]; e.J[6]=g[23]; e.J[7]=g[25]; e.J[8]=g[26];
  return e;
}
DEV FE fe_shfl_up(const FE& e, int d) {
  FE o;
#pragma unroll
  for (int i=0;i<9;++i) o.A[i]=__shfl_up(e.A[i], d, 64);
#pragma unroll
  for (int i=0;i<3;++i) o.b[i]=__shfl_up(e.b[i], d, 64);
  float c0=__shfl_up(e.C[0],d,64), c1=__shfl_up(e.C[1],d,64), c2=__shfl_up(e.C[2],d,64),
        c4=__shfl_up(e.C[4],d,64), c5=__shfl_up(e.C[5],d,64), c8=__shfl_up(e.C[8],d,64);
  o.C[0]=c0; o.C[1]=c1; o.C[2]=c2; o.C[3]=c1; o.C[4]=c4; o.C[5]=c5;
  o.C[6]=c2; o.C[7]=c5; o.C[8]=c8;
#pragma unroll
  for (int i=0;i<3;++i) o.h[i]=__shfl_up(e.h[i], d, 64);
  float j0=__shfl_up(e.J[0],d,64), j1=__shfl_up(e.J[1],d,64), j2=__shfl_up(e.J[2],d,64),
        j4=__shfl_up(e.J[4],d,64), j5=__shfl_up(e.J[5],d,64), j8=__shfl_up(e.J[8],d,64);
  o.J[0]=j0; o.J[1]=j1; o.J[2]=j2; o.J[3]=j1; o.J[4]=j4; o.J[5]=j5;
  o.J[6]=j2; o.J[7]=j5; o.J[8]=j8;
  return o;
}
DEV FE build_felem(const Model& M, float dt, float obsf, float rf, float Rf_, bool first) {
  FE E;
  float r = rf, R = Rf_;
  float g = (obsf > 0.5f) ? 1.0f : 0.0f;
  if (first) {
#pragma unroll
    for (int i=0;i<9;++i){ E.A[i]=0.0f; E.J[i]=0.0f; }
    E.h[0]=E.h[1]=E.h[2]=0.0f;
    float Pi[9]; pinf(M, Pi);
    float S = Pi[0] + R;
    float f = g / S;
    float K0=Pi[0]*f, K1=Pi[3]*f, K2=Pi[6]*f;
    E.b[0]=K0*r; E.b[1]=K1*r; E.b[2]=K2*r;
    E.C[0]=Pi[0]-S*K0*K0; E.C[1]=Pi[1]-S*K0*K1; E.C[2]=Pi[2]-S*K0*K2;
    E.C[3]=Pi[3]-S*K1*K0; E.C[4]=Pi[4]-S*K1*K1; E.C[5]=Pi[5]-S*K1*K2;
    E.C[6]=Pi[6]-S*K2*K0; E.C[7]=Pi[7]-S*K2*K1; E.C[8]=Pi[8]-S*K2*K2;
    return E;
  }
  float Am[9], Q[9]; make_AQ(M, dt, Am, Q);
  float S = Q[0] + R, iS = g / S;   // gated: obs=0 -> K=0, A=Am, C=Q, h=0, J=0
  float K0=Q[0]*iS, K1=Q[3]*iS, K2=Q[6]*iS;
#pragma unroll
  for (int j = 0; j < 3; ++j) {
    E.A[j]   = Am[j]   - K0*Am[j];
    E.A[3+j] = Am[3+j] - K1*Am[j];
    E.A[6+j] = Am[6+j] - K2*Am[j];
    E.C[j]   = Q[j]    - K0*Q[j];
    E.C[3+j] = Q[3+j]  - K1*Q[j];
    E.C[6+j] = Q[6+j]  - K2*Q[j];
  }
  E.b[0]=K0*r; E.b[1]=K1*r; E.b[2]=K2*r;
  float riS = r*iS;
  E.h[0]=Am[0]*riS; E.h[1]=Am[1]*riS; E.h[2]=Am[2]*riS;
#pragma unroll
  for (int i = 0; i < 3; ++i)
#pragma unroll
    for (int j = 0; j < 3; ++j)
      E.J[i*3+j] = Am[i]*Am[j]*iS;
  return E;
}
// compose: x earlier, y later
DEV FE fcompose(const FE& x, const FE& y) {
  const float *A1=x.A,*b1=x.b,*C1=x.C,*h1=x.h,*J1=x.J;
  const float *A2=y.A,*b2=y.b,*C2=y.C,*h2=y.h,*J2=y.J;
  FE o;
  float Mx[9]; mm(C1,J2,Mx); Mx[0]+=1.0f; Mx[4]+=1.0f; Mx[8]+=1.0f;
  float Mi[9]; inv3f(Mx,Mi);
  float T1[9]; mm(A2,Mi,T1);
  mm(T1,A1,o.A);
  float u[3]; mv(C1,h2,u); u[0]+=b1[0]; u[1]+=b1[1]; u[2]+=b1[2];
  mv(T1,u,o.b); o.b[0]+=b2[0]; o.b[1]+=b2[1]; o.b[2]+=b2[2];
  float t2[9]; mm(T1,C1,t2);
  mmnt(t2,A2,o.C);
#pragma unroll
  for (int i=0;i<9;++i) o.C[i]+=C2[i];
  float tmp[9]; mm(Mi,A1,tmp);
  float w[3]; mv(J2,b1,w);
  w[0]=h2[0]-w[0]; w[1]=h2[1]-w[1]; w[2]=h2[2]-w[2];
  mtv(tmp,w,o.h); o.h[0]+=h1[0]; o.h[1]+=h1[1]; o.h[2]+=h1[2];
  float V[9]; mm(J2,A1,V);
  mtn(tmp,V,o.J);
#pragma unroll
  for (int i=0;i<9;++i) o.J[i]+=J1[i];
  symm(o.C); symm(o.J);
  return o;
}
// apply element y (later) to a state (m,P)
DEV void fapply(const FE& y, float* m, float* P) {
  float Mx[9]; mm(P, y.J, Mx); Mx[0]+=1.0f; Mx[4]+=1.0f; Mx[8]+=1.0f;
  float Mi[9]; inv3f(Mx, Mi);
  float T1[9]; mm(y.A, Mi, T1);
  float u[3]; mv(P, y.h, u); u[0]+=m[0]; u[1]+=m[1]; u[2]+=m[2];
  float mn[3]; mv(T1, u, mn);
  m[0]=mn[0]+y.b[0]; m[1]=mn[1]+y.b[1]; m[2]=mn[2]+y.b[2];
  float t2[9]; mm(T1, P, t2);
  float Pn[9]; mmnt(t2, y.A, Pn);
#pragma unroll
  for (int i=0;i<9;++i) P[i]=Pn[i]+y.C[i];
  symm(P);
}
// plain Kalman step (replay)
DEV void fstep(const Model& M, float dt, float obsf, float rf, float Rf_,
               float* m, float* P) {
  float A[9], Q[9]; make_AQ(M, dt, A, Q);
  float mp[3]; mv(A, m, mp);
  float W[9]; mmnt(P, A, W);      // P A^T
  float Pp[9]; mm(A, W, Pp);
#pragma unroll
  for (int i=0;i<9;++i) Pp[i]+=Q[i];
  float S = Pp[0] + Rf_;
  float f = (obsf > 0.5f) ? (1.0f/S) : 0.0f;
  float K0=Pp[0]*f, K1=Pp[3]*f, K2=Pp[6]*f;
  float v = rf - mp[0];
  m[0]=mp[0]+K0*v; m[1]=mp[1]+K1*v; m[2]=mp[2]+K2*v;
  P[0]=Pp[0]-S*K0*K0; P[1]=Pp[1]-S*K0*K1; P[2]=Pp[2]-S*K0*K2;
  P[3]=Pp[3]-S*K1*K0; P[4]=Pp[4]-S*K1*K1; P[5]=Pp[5]-S*K1*K2;
  P[6]=Pp[6]-S*K2*K0; P[7]=Pp[7]-S*K2*K1; P[8]=Pp[8]-S*K2*K2;
  symm(P);
}

// ---------------- smoother affine map ----------------
struct SE { float G[9]; float c[3]; float U[9]; };

DEV SE se_identity() {
  SE s;
#pragma unroll
  for (int i=0;i<9;++i){ s.G[i]=0.0f; s.U[i]=0.0f; }
  s.G[0]=s.G[4]=s.G[8]=1.0f;
  s.c[0]=s.c[1]=s.c[2]=0.0f;
  return s;
}
DEV void se_store(const SE& s, float* g) {   // contiguous packed-18
#pragma unroll
  for (int i=0;i<9;++i) g[i]=s.G[i];
  g[9]=s.c[0]; g[10]=s.c[1]; g[11]=s.c[2];
  g[12]=s.U[0]; g[13]=s.U[1]; g[14]=s.U[2]; g[15]=s.U[4]; g[16]=s.U[5]; g[17]=s.U[8];
}
DEV SE se_load(const float* g) {
  SE s;
#pragma unroll
  for (int i=0;i<9;++i) s.G[i]=g[i];
  s.c[0]=g[9]; s.c[1]=g[10]; s.c[2]=g[11];
  s.U[0]=g[12]; s.U[1]=g[13]; s.U[2]=g[14];
  s.U[3]=g[13]; s.U[4]=g[15]; s.U[5]=g[16];
  s.U[6]=g[14]; s.U[7]=g[16]; s.U[8]=g[17];
  return s;
}
DEV SE se_shfl_down(const SE& s, int d) {
  SE o;
#pragma unroll
  for (int i=0;i<9;++i) o.G[i]=__shfl_down(s.G[i], d, 64);
#pragma unroll
  for (int i=0;i<3;++i) o.c[i]=__shfl_down(s.c[i], d, 64);
  float u0=__shfl_down(s.U[0],d,64), u1=__shfl_down(s.U[1],d,64), u2=__shfl_down(s.U[2],d,64),
        u4=__shfl_down(s.U[4],d,64), u5=__shfl_down(s.U[5],d,64), u8=__shfl_down(s.U[8],d,64);
  o.U[0]=u0; o.U[1]=u1; o.U[2]=u2; o.U[3]=u1; o.U[4]=u4; o.U[5]=u5;
  o.U[6]=u2; o.U[7]=u5; o.U[8]=u8;
  return o;
}
// x earlier in time (applied LAST, since smoother runs backward)
DEV SE scompose(const SE& x, const SE& y) {
  SE o;
  mm(x.G, y.G, o.G);
  float t[3]; mv(x.G, y.c, t);
  o.c[0]=t[0]+x.c[0]; o.c[1]=t[1]+x.c[1]; o.c[2]=t[2]+x.c[2];
  float T[9]; mm(x.G, y.U, T);
  mmnt(T, x.G, o.U);
#pragma unroll
  for (int i=0;i<9;++i) o.U[i]+=x.U[i];
  symm(o.U);
  return o;
}
DEV void sapply(const SE& s, float* m, float* P) {
  float t[3]; mv(s.G, m, t);
  float T[9]; mm(s.G, P, T);
  float Pn[9]; mmnt(T, s.G, Pn);
  m[0]=t[0]+s.c[0]; m[1]=t[1]+s.c[1]; m[2]=t[2]+s.c[2];
#pragma unroll
  for (int i=0;i<9;++i) P[i]=Pn[i]+s.U[i];
  symm(P);
}
DEV SE selem_from_state(const Model& M, const float* m, const float* P, float dtn) {
  SE s;
  float A[9], Q[9]; make_AQ(M, dtn, A, Q);
  float W[9]; mmnt(P, A, W);      // P A^T
  float Pp[9]; mm(A, W, Pp);
#pragma unroll
  for (int j=0;j<9;++j) Pp[j]+=Q[j];
  float Pi_[9]; inv3d(Pp, Pi_);    // ill-conditioned -> double cofactors
  mm(W, Pi_, s.G);                 // G = P A^T Pp^-1
  float mp[3]; mv(A, m, mp);
  float gm[3]; mv(s.G, mp, gm);
  s.c[0]=m[0]-gm[0]; s.c[1]=m[1]-gm[1]; s.c[2]=m[2]-gm[2];
  float GW[9]; mmnt(s.G, W, GW);   // G Pp G^T
#pragma unroll
  for (int j=0;j<9;++j) s.U[j]=P[j]-GW[j];
  symm(s.U);
  return s;
}

// ---------------- device-wide barrier (two-level, agent scope) ----------------
// Spin is RELAXED (no per-poll cache invalidate); one acquire fence on exit.
DEV void grid_sync(int* bar, int grp) {
  __syncthreads();
  if (threadIdx.x == 0) {
    int* gen = bar + 257;
    int g = __hip_atomic_load(gen, __ATOMIC_RELAXED, __HIP_MEMORY_SCOPE_AGENT);
    asm volatile("s_waitcnt vmcnt(0)" ::: "memory");   // g in hand before arrival
    int* gc = bar + grp*16;
    if (__hip_atomic_fetch_add(gc, 1, __ATOMIC_RELEASE, __HIP_MEMORY_SCOPE_AGENT)
        == BLKS_PER_GRP-1) {
      __hip_atomic_store(gc, 0, __ATOMIC_RELAXED, __HIP_MEMORY_SCOPE_AGENT);
      int* cnt = bar + 256;
      if (__hip_atomic_fetch_add(cnt, 1, __ATOMIC_RELEASE, __HIP_MEMORY_SCOPE_AGENT)
          == NGRP_BAR-1) {
        __hip_atomic_store(cnt, 0, __ATOMIC_RELAXED, __HIP_MEMORY_SCOPE_AGENT);
        __hip_atomic_store(gen, g+1, __ATOMIC_RELEASE, __HIP_MEMORY_SCOPE_AGENT);
      }
    }
    while (__hip_atomic_load(gen, __ATOMIC_RELAXED, __HIP_MEMORY_SCOPE_AGENT) == g) {
      __builtin_amdgcn_s_sleep(1);
    }
    __builtin_amdgcn_fence(__ATOMIC_ACQUIRE, "agent");
  }
  __syncthreads();
}

// ================= kernels =================
__global__ void k_init(int* bar) {
  int i = threadIdx.x;
  if (i < 258) bar[i] = 0;
}

// Persistent kernel, 3 grid barriers, 2 elems/thread, 768 blocks x 2 waves.
// __launch_bounds__(128,2): VGPR cap 256, natural use ~128 (round 3: no spill).
// Round-5 lesson: forcing 4 waves/EU caused 64-VGPR + 77MB scratch spill; never
// cap below the kernel's ~130-VGPR natural demand.
// Mid-scans: 768 aggregates distributed 6/thread over 128 threads (round-5
// pattern, correctness-proven); results parked in LDS; extraction = LDS state
// + <=5 block-uniform applies. ldsB stride 19 floats (bank-conflict-free).
__global__ __launch_bounds__(TPB, 2) void k_fused(
    const float* __restrict__ times, const float* __restrict__ tstar,
    const float* __restrict__ n1, const float* __restrict__ n2,
    const float* __restrict__ varp, const float* __restrict__ ellp,
    const float* __restrict__ mcp,
    float4* __restrict__ pk, int* __restrict__ oix,
    float* __restrict__ blkAgg, float* __restrict__ blkAggS,
    float* __restrict__ xT, int* __restrict__ bar, float* __restrict__ out) {
  __shared__ float ldsA[WPB][27];     // wave totals (FE 27 / SE 18)
  __shared__ float ldsB[TPB][19];     // per-thread prefix states / suffix SEs
  const int tid = threadIdx.x, b = blockIdx.x;
  const int l = tid & 63, w = tid >> 6;
  const int grp = b & (NGRP_BAR-1);
  Model M = make_model(varp, ellp);
  const float mc = mcp[0];

  // ---- phase 0: merge (2 global items per thread) ----
  {
    int T = b*TPB + tid;
#pragma unroll
    for (int rep = 0; rep < 2; ++rep) {
      int g = T + rep*(NB*TPB);
      if (g < N_TRAIN) {
        int i = g; float t = times[i];
        int lo = 0, hi = M_TEST;                 // count tstar strictly < t
        while (lo < hi) { int mid=(lo+hi)>>1; if (tstar[mid] < t) lo=mid+1; else hi=mid; }
        int p = i + lo;
        float s2 = n2[i];
        pk[p] = make_float4(t, n1[i]/s2 - mc, 1.0f/s2, 1.0f);
        oix[p] = -1;
      } else {
        int j = g - N_TRAIN; float t = tstar[j];
        int lo = 0, hi = N_TRAIN;                // count times <= t (stable: train first)
        while (lo < hi) { int mid=(lo+hi)>>1; if (times[mid] <= t) lo=mid+1; else hi=mid; }
        int p = j + lo;
        pk[p] = make_float4(t, 0.f, 1.f, 0.f);
        oix[p] = j;
      }
    }
  }
  grid_sync(bar, grp);                            // A: wrote pk/oix; all read pk

  // ---- phase 1: forward pair-scan; exclusive-in-block FE in registers ----
  const int i0 = b*EPB + w*EPW + 2*l;
  const int i1 = i0 + 1;
  float4 q0 = pk[i0], q1 = pk[i1];
  float tm1 = (i0 > 0) ? pk[i0-1].x : 0.0f;
  const float dt0  = (i0 == 0) ? 0.0f : (q0.x - tm1);
  const float dt01 = q1.x - q0.x;
  FE ex; bool has;
  {
    FE E0 = build_felem(M, dt0,  q0.w, q0.y, q0.z, i0 == 0);
    FE E1 = build_felem(M, dt01, q1.w, q1.y, q1.z, false);
    FE run = fcompose(E0, E1);
    for (int d = 1; d < 64; d <<= 1) {
      FE oth = fe_shfl_up(run, d);
      FE c = fcompose(oth, run);
      if (l >= d) run = c;
    }
    if (l == 63) fe_store27(run, ldsA[w]);
    FE exw = fe_shfl_up(run, 1);
    __syncthreads();
    has = false;
    if (l > 0) { ex = exw; has = true; }
    for (int k = w-1; k >= 0; --k) {            // wave-uniform
      FE wk = fe_load27(ldsA[k]);
      ex = has ? fcompose(wk, ex) : wk;
      has = true;
    }
    if (tid == TPB-1) {                         // block aggregate
      FE agg = run;
      for (int k = w-1; k >= 0; --k) agg = fcompose(fe_load27(ldsA[k]), agg);
      fe_store27(agg, blkAgg + b*27);
    }
  }
  grid_sync(bar, grp);                            // B: wrote blkAgg; all read it

  // ---- phase 2: distributed mid-scan (6 aggs/thread) -> entry state ----
  float mE[3], PE[9];
  {
    {
      FE run = fe_load27(blkAgg + (tid*PER_T)*27);
      for (int i = 1; i < PER_T; ++i)
        run = fcompose(run, fe_load27(blkAgg + (tid*PER_T+i)*27));
      for (int d = 1; d < 64; d <<= 1) {
        FE oth = fe_shfl_up(run, d);
        FE c = fcompose(oth, run);
        if (l >= d) run = c;
      }
      if (w == 0 && l == 63) fe_store27(run, ldsA[0]);   // wave-0 total: aggs [0,384)
      __syncthreads();
      if (w == 1) run = fcompose(fe_load27(ldsA[0]), run);
      // run covers aggs [0, 6*tid+5]; includes agg 0 -> (b,C) is a state
      ldsB[tid][0]=run.b[0]; ldsB[tid][1]=run.b[1]; ldsB[tid][2]=run.b[2];
      ldsB[tid][3]=run.C[0]; ldsB[tid][4]=run.C[1]; ldsB[tid][5]=run.C[2];
      ldsB[tid][6]=run.C[4]; ldsB[tid][7]=run.C[5]; ldsB[tid][8]=run.C[8];
    }
    __syncthreads();
    // extraction (block-uniform): prefix over aggs [0, b)
    int full = b / PER_T;                       // threads [0,full) fully in prefix
    if (full == 0) { mE[0]=mE[1]=mE[2]=0.0f; pinf(M, PE); }
    else ld_state(&ldsB[full-1][0], mE, PE);
    for (int i = full*PER_T; i < b; ++i) {      // <=5 block-uniform applies
      FE y = fe_load27(blkAgg + i*27);
      fapply(y, mE, PE);
    }
  }

  // ---- phase 3: replay (2 fsteps) + smoother elements + backward in-block scan ----
  float r0[5], r1[5];  // row-0 of suffix map for elems i0, i1 (kept in regs)
  {
    float m[3] = { mE[0], mE[1], mE[2] };
    float P[9];
#pragma unroll
    for (int i=0;i<9;++i) P[i]=PE[i];
    if (has) fapply(ex, m, P);
    fstep(M, dt0, q0.w, q0.y, q0.z, m, P);
    SE s0 = selem_from_state(M, m, P, dt01);
    fstep(M, dt01, q1.w, q1.y, q1.z, m, P);
    SE s1;
    if (i1 == T_TOT-1) {
      s1 = se_identity();
      st_state(m, P, xT);
    } else {
      float tn = pk[i1+1].x;
      s1 = selem_from_state(M, m, P, tn - q1.x);
    }
    SE ps = scompose(s0, s1);
    SE run = ps;
    for (int d = 1; d < 64; d <<= 1) {
      SE oth = se_shfl_down(run, d);
      SE c = scompose(run, oth);
      if (l + d < 64) run = c;
    }
    SE sx = se_shfl_down(run, 1);
    __syncthreads();                            // ldsB reads of phase 2 done
    if (l == 0) se_store(run, ldsA[w]);
    __syncthreads();
    SE S; bool hs = false;
    if (l < 63) { S = sx; hs = true; }
    for (int k = w+1; k < WPB; ++k) {           // wave-uniform
      SE wk = se_load(ldsA[k]);
      S = hs ? scompose(S, wk) : wk;
      hs = true;
    }
    SE M1 = hs ? scompose(s1, S) : s1;
    SE M0 = scompose(s0, M1);
    r0[0]=M0.G[0]; r0[1]=M0.G[1]; r0[2]=M0.G[2]; r0[3]=M0.c[0]; r0[4]=M0.U[0];
    r1[0]=M1.G[0]; r1[1]=M1.G[1]; r1[2]=M1.G[2]; r1[3]=M1.c[0]; r1[4]=M1.U[0];
    if (tid == 0) se_store(M0, blkAggS + b*18); // tid 0's M0 spans whole block
  }
  grid_sync(bar, grp);                            // D: wrote blkAggS/xT; all read

  // ---- phase 4: distributed mid-scan (6 aggs/thread) -> exit state ----
  float mX[3], PX[9];
  {
    {
      SE run = se_load(blkAggS + (tid*PER_T)*18);
      for (int i = 1; i < PER_T; ++i)
        run = scompose(run, se_load(blkAggS + (tid*PER_T+i)*18));
      for (int d = 1; d < 64; d <<= 1) {
        SE oth = se_shfl_down(run, d);
        SE c = scompose(run, oth);
        if (l + d < 64) run = c;
      }
      if (w == 1 && l == 0) se_store(run, ldsA[0]);   // wave-1 total: aggs [384,768)
      __syncthreads();
      if (w == 0) run = scompose(run, se_load(ldsA[0]));
      // run = suffix SE over aggs [6*tid, 767]
      se_store(run, &ldsB[tid][0]);
    }
    __syncthreads();
    // extraction (block-uniform): state at first elem of block b+1
    mX[0]=xT[0]; mX[1]=xT[1]; mX[2]=xT[2];
    PX[0]=xT[3]; PX[1]=xT[4]; PX[2]=xT[5];
    PX[3]=xT[4]; PX[4]=xT[6]; PX[5]=xT[7];
    PX[6]=xT[5]; PX[7]=xT[7]; PX[8]=xT[8];
    if (b < NB-1) {
      int e = b + 1;                            // suffix needed: aggs [e, NB-1]
      int ct = (e + PER_T - 1) / PER_T;         // first thread fully inside suffix
      if (ct < TPB) { SE sb = se_load(&ldsB[ct][0]); sapply(sb, mX, PX); }
      for (int i = ct*PER_T - 1; i >= e; --i) { // <=5 block-uniform applies
        SE y = se_load(blkAggS + i*18);
        sapply(y, mX, PX);
      }
    }
  }

  // ---- phase 5: outputs ----
  {
    int jo0 = oix[i0], jo1 = oix[i1];
    if (jo0 >= 0) {
      float mm0 = r0[0]*mX[0] + r0[1]*mX[1] + r0[2]*mX[2] + r0[3];
      float a0 = r0[0]*PX[0] + r0[1]*PX[3] + r0[2]*PX[6];
      float a1 = r0[0]*PX[1] + r0[1]*PX[4] + r0[2]*PX[7];
      float a2 = r0[0]*PX[2] + r0[1]*PX[5] + r0[2]*PX[8];
      float v00 = a0*r0[0] + a1*r0[1] + a2*r0[2] + r0[4];
      out[jo0] = mm0 + mc; out[M_TEST + jo0] = fmaxf(v00, 0.0f);
    }
    if (jo1 >= 0) {
      float mm0 = r1[0]*mX[0] + r1[1]*mX[1] + r1[2]*mX[2] + r1[3];
      float a0 = r1[0]*PX[0] + r1[1]*PX[3] + r1[2]*PX[6];
      float a1 = r1[0]*PX[1] + r1[1]*PX[4] + r1[2]*PX[7];
      float a2 = r1[0]*PX[2] + r1[1]*PX[5] + r1[2]*PX[8];
      float v00 = a0*r1[0] + a1*r1[1] + a2*r1[2] + r1[4];
      out[jo1] = mm0 + mc; out[M_TEST + jo1] = fmaxf(v00, 0.0f);
    }
  }
}

extern "C" void kernel_launch(void* const* d_in, const int* in_sizes, int n_in,
                              void* d_out, int out_size, void* d_ws, size_t ws_size,
                              hipStream_t stream) {
  const float* times = (const float*)d_in[0];
  const float* tstar = (const float*)d_in[1];
  const float* n1    = (const float*)d_in[2];
  const float* n2    = (const float*)d_in[3];
  const float* varp  = (const float*)d_in[4];
  const float* ellp  = (const float*)d_in[5];
  const float* mcp   = (const float*)d_in[6];
  float* out = (float*)d_out;

  size_t off = 0;
  auto take = [&](size_t bytes) {
    char* p = (char*)d_ws + off;
    off += (bytes + 255) & ~(size_t)255;
    return (void*)p;
  };
  float4* pk      = (float4*)take(sizeof(float4) * T_TOT);
  int*    oix     = (int*)   take(sizeof(int)    * T_TOT);
  float*  blkAgg  = (float*) take(sizeof(float)  * 27 * NB);
  float*  blkAggS = (float*) take(sizeof(float)  * 18 * NB);
  float*  xT      = (float*) take(sizeof(float)  * 16);
  int*    bar     = (int*)   take(sizeof(int)    * 512);
  (void)ws_size; (void)in_sizes; (void)n_in; (void)out_size;

  k_init<<<1, 512, 0, stream>>>(bar);
  k_fused<<<NB, TPB, 0, stream>>>(times, tstar, n1, n2, varp, ellp, mcp,
                                  pk, oix, blkAgg, blkAggS, xT, bar, out);
}